// Round 13
// baseline (136.173 us; speedup 1.0000x reference)
//
#include <hip/hip_runtime.h>
#include <hip/hip_bf16.h>
#include <stdint.h>

// Shapes (fixed): B=16, C=512, L=1024, H=8, ch=64, groups=32

using f32x4  = __attribute__((ext_vector_type(4))) float;
using bf16x8 = __attribute__((ext_vector_type(8))) __bf16;
using s8v    = __attribute__((ext_vector_type(8))) short;
using s4v    = __attribute__((ext_vector_type(4))) short;

__device__ __forceinline__ short f2bf(float f){
  union { float f; unsigned u; } c; c.f = f;
  unsigned r = (c.u + 0x7FFFu + ((c.u >> 16) & 1u)) >> 16;   // RNE
  return (short)r;
}

__device__ __forceinline__ float exp2_fast(float x){
#if __has_builtin(__builtin_amdgcn_exp2f)
  return __builtin_amdgcn_exp2f(x);
#else
  return exp2f(x);
#endif
}

// async global->LDS, 16B per lane
__device__ __forceinline__ void gl_lds16(const void* g, void* l){
  __builtin_amdgcn_global_load_lds((const __attribute__((address_space(1))) void*)g,
                                   (__attribute__((address_space(3))) void*)l, 16, 0, 0);
}

// ---------------- fused: GroupNorm (blocks 0..511) + weight convert (blocks 512+) ----------------
__global__ __launch_bounds__(256) void k_pre(const float* __restrict__ x,
                                             const float* __restrict__ w,
                                             const float* __restrict__ bia,
                                             short* __restrict__ hid,
                                             const float* __restrict__ qw,
                                             const float* __restrict__ pw,
                                             const float* __restrict__ qb,
                                             short* __restrict__ qwb,
                                             short* __restrict__ pwb,
                                             float* __restrict__ qbp){
  int bid = blockIdx.x;
  int tid = threadIdx.x;
  if (bid >= 512){
    int i = (bid - 512) * 256 + tid;
    if (i < 786432){
      int o = i >> 9, kk = i & 511;
      int h = o / 192, rem = o - h*192;
      int nr = (rem >> 6)*512 + h*64 + (rem & 63);   // q|k|v row blocks
      qwb[nr*512 + kk] = f2bf(qw[i]);
    } else if (i < 1048576){
      int j = i - 786432;
      pwb[j] = f2bf(pw[j]);
    } else if (i < 1050112){
      int o = i - 1048576;
      int h = o / 192, rem = o - h*192;
      qbp[(rem >> 6)*512 + h*64 + (rem & 63)] = qb[o];
    }
    return;
  }
  int b = bid >> 5;
  int g = bid & 31;
  const float* xg = x + ((size_t)b*512 + g*16)*1024;
  int l0 = tid * 4;
  float v[16][4];
  float s1 = 0.f, s2 = 0.f;
  #pragma unroll
  for (int c = 0; c < 16; c++){
    f32x4 t = *(const f32x4*)(xg + c*1024 + l0);
    #pragma unroll
    for (int j = 0; j < 4; j++){ v[c][j] = t[j]; s1 += t[j]; s2 += t[j]*t[j]; }
  }
  #pragma unroll
  for (int m = 32; m; m >>= 1){ s1 += __shfl_xor(s1, m); s2 += __shfl_xor(s2, m); }
  __shared__ float r1[4], r2[4];
  int wv = tid >> 6, ln = tid & 63;
  if (ln == 0){ r1[wv] = s1; r2[wv] = s2; }
  __syncthreads();
  s1 = r1[0]+r1[1]+r1[2]+r1[3];
  s2 = r2[0]+r2[1]+r2[2]+r2[3];
  float mu = s1 * (1.f/16384.f);
  float var = s2 * (1.f/16384.f) - mu*mu;
  float rs = rsqrtf(var + 1e-5f);
  float ww[16], bb[16];
  #pragma unroll
  for (int c = 0; c < 16; c++){ ww[c] = w[g*16+c]*rs; bb[c] = bia[g*16+c]; }
  #pragma unroll
  for (int j = 0; j < 4; j++){
    short o[16];
    #pragma unroll
    for (int c = 0; c < 16; c++) o[c] = f2bf((v[c][j]-mu)*ww[c] + bb[c]);
    short* dst = hid + ((size_t)(b*1024 + l0 + j))*512 + g*16;
    *(s8v*)dst     = *(s8v*)o;
    *(s8v*)(dst+8) = *(s8v*)(o+8);
  }
}

// ---------------- QKV GEMM: BM=256, BN=128, BK=32; 4 waves, wave tile 128x64 ----------------
// Intensity-balanced: 12 ds_read_b128 -> 32 MFMA per wave-iter. 2-buf 48KB.
// Race-sealed sync (R12-proven): __syncthreads(); STAGE(t+1); COMPUTE(t).
// v_t cell layout per (bh, s>>6) region of 4096 shorts:
//   idx = (((ks*4+gq)*4 + (c>>4))*16 + (c&15))*8 + (sl&3) + 4*((sl>>4)&1)
__global__ __launch_bounds__(256) void k_gemmQ(
    const short* __restrict__ A, const short* __restrict__ Bm,
    const float* __restrict__ bias,
    short* __restrict__ q_t, short* __restrict__ k_t, short* __restrict__ v_t)
{
  __shared__ short Lds[24576];   // 48KB: 2 bufs x (A 16KB + B 8KB)
  int id = blockIdx.x;           // 768
  int xcd = id & 7, ix = id >> 3;          // 96 per xcd
  int mt = ix % 6, nt = ix / 6;            // m-fastest: 6 m-tiles share each B-panel
  int m0 = mt * 256;
  int n0 = (xcd + 8*nt) * 128;
  int tid = threadIdx.x;
  int lane = tid & 63;
  int wv = tid >> 6;
  int wr = wv >> 1, wc = wv & 1;           // wave tile 128m x 64n
  int l15 = lane & 15, g = lane >> 4;
  f32x4 acc[8][4] = {};

  auto STAGE = [&](int db, int t){
    int k0 = t * 32;
    #pragma unroll
    for (int i = 0; i < 6; i++){
      int cc = wv*6 + i;                   // 24 chunks of 1KB (16 A + 8 B)
      int row, byteoff;
      const short* srcb;
      if (cc < 16){ row = cc*16 + (lane>>2); srcb = A + (size_t)(m0+row)*512; byteoff = cc*1024; }
      else        { row = (cc-16)*16 + (lane>>2); srcb = Bm + (size_t)(n0+row)*512; byteoff = 16384 + (cc-16)*1024; }
      int slot = lane & 3;
      gl_lds16(srcb + k0 + ((slot ^ ((row>>1)&3))*8),
               (char*)Lds + db*24576 + byteoff);
    }
  };

  auto COMPUTE = [&](int db){
    const char* Ab = (const char*)Lds + db*24576;
    const char* Bb = Ab + 16384;
    bf16x8 af[8], bf[4];
    #pragma unroll
    for (int m = 0; m < 8; m++){
      int row = wr*128 + m*16 + l15;
      af[m] = *(const bf16x8*)(Ab + row*64 + ((g*16) ^ (((row>>1)&3)<<4)));
    }
    #pragma unroll
    for (int n = 0; n < 4; n++){
      int row = wc*64 + n*16 + l15;
      bf[n] = *(const bf16x8*)(Bb + row*64 + ((g*16) ^ (((row>>1)&3)<<4)));
    }
    __builtin_amdgcn_s_setprio(1);
    #pragma unroll
    for (int m = 0; m < 8; m++)
      #pragma unroll
      for (int n = 0; n < 4; n++)
        acc[m][n] = __builtin_amdgcn_mfma_f32_16x16x32_bf16(af[m], bf[n], acc[m][n], 0, 0, 0);
    __builtin_amdgcn_s_setprio(0);
  };

  STAGE(0, 0);
  for (int t = 0; t < 16; t++){
    __syncthreads();                 // full fence+barrier (race-sealed)
    if (t < 15) STAGE((t+1)&1, t+1);
    COMPUTE(t&1);
  }

  int sel = m0 >> 9;               // m0 in {0,256,512,768,1024,1280} -> 0,0,1,1,2,2
  if (sel < 2){
    const float sc = (sel == 0) ? 0.18033688011112042f : 1.0f;  // 2^-3 * log2(e) folded into q
    short* dstb = (sel == 0) ? q_t : k_t;
    #pragma unroll
    for (int m = 0; m < 8; m++){
      int ob = m0 + wr*128 + m*16 + (g<<2);
      int hh = (ob>>6)&7, c0 = ob&63;
      float bs[4];
      #pragma unroll
      for (int r = 0; r < 4; r++) bs[r] = bias[ob+r];
      #pragma unroll
      for (int n = 0; n < 4; n++){
        int nn = n0 + wc*64 + n*16 + l15;
        int bb = nn >> 10, ll = nn & 1023;
        int bh = bb*8 + hh;
        short o4[4];
        #pragma unroll
        for (int r = 0; r < 4; r++) o4[r] = f2bf((acc[m][n][r] + bs[r]) * sc);
        *(s4v*)(dstb + ((size_t)bh*1024 + ll)*64 + c0) = *(s4v*)o4;
      }
    }
  } else {
    // v tile 256m x 128n = 64KB image -> two 32KB phases (head-pairs) in 48KB LDS
    short* Sc = Lds;
    int b0  = n0 >> 10;
    int s64 = (n0 >> 6) & 15;
    int hb  = (m0 - 1024) >> 6;      // 0 or 4
    #pragma unroll
    for (int ph = 0; ph < 2; ph++){
      __syncthreads();               // previous readers (K-loop or copy-out) done
      if (wr == ph){
        #pragma unroll
        for (int m = 0; m < 8; m++){
          int ob = m0 + wr*128 + m*16 + (g<<2);
          int h2 = (ob>>6)&1, cq = (ob>>4)&3;
          float bs[4];
          #pragma unroll
          for (int r = 0; r < 4; r++) bs[r] = bias[ob+r];
          #pragma unroll
          for (int n = 0; n < 4; n++){
            int nn = n0 + wc*64 + n*16 + l15;
            int sl = nn & 63, sreg = (nn>>6)&1;
            int ks2 = sl >> 5, gq = (sl>>2)&3, i2 = (sl&3) + 4*((sl>>4)&1);
            int base = (h2*2 + sreg)*4096 + (((ks2*4+gq)*4 + cq)*16 + (g<<2))*8 + i2;
            #pragma unroll
            for (int r = 0; r < 4; r++)
              Sc[base + r*8] = f2bf(acc[m][n][r] + bs[r]);
          }
        }
      }
      __syncthreads();
      #pragma unroll
      for (int it = 0; it < 8; it++){
        int flat = it*2048 + tid*8;      // 16384 shorts per phase
        int reg = flat >> 12, off = flat & 4095;
        int h2 = reg >> 1, sreg = reg & 1;
        int bh = b0*8 + hb + ph*2 + h2;
        *(s8v*)(v_t + ((size_t)bh*16 + s64 + sreg)*4096 + off) = *(const s8v*)(Sc + flat);
      }
    }
  }
}

// ---------------- Proj GEMM: R12-proven 128x128, BK=64, 2-buf, __syncthreads ----------------
__global__ __launch_bounds__(256) void k_gemmP(
    const short* __restrict__ A, const short* __restrict__ Bm,
    const float* __restrict__ bias, const float* __restrict__ xres,
    float* __restrict__ outp)
{
  __shared__ short Al[2][128*64];
  __shared__ short Bl[2][128*64];
  int id = blockIdx.x;
  int xcd = id & 7, ix = id >> 3;
  int mt = ix & 3, nt = ix >> 2;
  int m0 = mt * 128;
  int n0 = (xcd + 8*nt) * 128;
  int tid = threadIdx.x;
  int lane = tid & 63;
  int wv = tid >> 6;
  int wr = wv >> 1, wc = wv & 1;
  int l15 = lane & 15, g = lane >> 4;
  f32x4 acc[4][4] = {};

  auto STAGE = [&](int db, int t){
    int k0 = t * 64;
    #pragma unroll
    for (int i = 0; i < 8; i++){
      int cc = wv*8 + i;
      if (cc < 16){
        int slot = cc*64 + lane;
        int row = slot >> 3, off = slot & 7;
        gl_lds16(A + (size_t)(m0+row)*512 + k0 + (off ^ (row&7))*8,
                 (char*)Al[db] + cc*1024);
      } else {
        int slot = (cc-16)*64 + lane;
        int row = slot >> 3, off = slot & 7;
        gl_lds16(Bm + (size_t)(n0+row)*512 + k0 + (off ^ (row&7))*8,
                 (char*)Bl[db] + (cc-16)*1024);
      }
    }
  };

  auto COMPUTE = [&](int db){
    #pragma unroll
    for (int kk = 0; kk < 2; kk++){
      bf16x8 af[4], bf[4];
      #pragma unroll
      for (int m = 0; m < 4; m++){
        int row = wr*64 + m*16 + l15;
        int byte = row*128 + (((kk*64) + (g*16)) ^ ((row&7)<<4));
        af[m] = *(const bf16x8*)((char*)Al[db] + byte);
      }
      #pragma unroll
      for (int n = 0; n < 4; n++){
        int row = wc*64 + n*16 + l15;
        int byte = row*128 + (((kk*64) + (g*16)) ^ ((row&7)<<4));
        bf[n] = *(const bf16x8*)((char*)Bl[db] + byte);
      }
      __builtin_amdgcn_s_setprio(1);
      #pragma unroll
      for (int m = 0; m < 4; m++)
        #pragma unroll
        for (int n = 0; n < 4; n++)
          acc[m][n] = __builtin_amdgcn_mfma_f32_16x16x32_bf16(af[m], bf[n], acc[m][n], 0, 0, 0);
      __builtin_amdgcn_s_setprio(0);
    }
  };

  STAGE(0, 0);
  for (int t = 0; t < 8; t++){
    __syncthreads();
    if (t < 7) STAGE((t+1)&1, t+1);
    COMPUTE(t&1);
  }

  #pragma unroll
  for (int m = 0; m < 4; m++){
    int ob = m0 + wr*64 + m*16 + (g<<2);
    float bs[4];
    #pragma unroll
    for (int r = 0; r < 4; r++) bs[r] = bias[ob+r];
    #pragma unroll
    for (int n = 0; n < 4; n++){
      int nn = n0 + wc*64 + n*16 + l15;
      int bb = nn >> 10, ll = nn & 1023;
      #pragma unroll
      for (int r = 0; r < 4; r++){
        size_t idx = ((size_t)bb*512 + ob + r)*1024 + ll;
        outp[idx] = xres[idx] + acc[m][n][r] + bs[r];
      }
    }
  }
}

// ---------------- Flash attention: 4-half-buffer counted-vmcnt pipeline (frozen, R12) ----------------
__global__ __launch_bounds__(256, 4) void k_attn(
    const short* __restrict__ q_t, const short* __restrict__ k_t,
    const short* __restrict__ v_t, short* __restrict__ a_bt)
{
  __shared__ short Kh[4*2048];
  __shared__ short Vh[4*2048];
  int id = blockIdx.x;                 // 1024
  int xcd = id & 7, ix = id >> 3;
  int bh = xcd*16 + (ix >> 3);
  int qb = ix & 7;
  int bb = bh >> 3, hh = bh & 7;
  int tid = threadIdx.x;
  int lane = tid & 63;
  int wv = tid >> 6;
  int l15 = lane & 15, g = lane >> 4;

  bf16x8 qf[2][2];
  #pragma unroll
  for (int qt = 0; qt < 2; qt++){
    const short* qbase = q_t + ((size_t)bh*1024 + qb*128 + qt*64 + wv*16 + l15)*64 + g*8;
    qf[qt][0] = *(const bf16x8*)(qbase);
    qf[qt][1] = *(const bf16x8*)(qbase + 32);
  }
  asm volatile("" :: "v"(qf[0][0]), "v"(qf[0][1]), "v"(qf[1][0]), "v"(qf[1][1]));

  bf16x8 onesb;
  #pragma unroll
  for (int i = 0; i < 8; i++) onesb[i] = (__bf16)1.0f;

  f32x4 o[2][4] = {};
  f32x4 osum[2] = {};

  auto STAGE = [&](int db, int h){
    int t64 = h >> 1, ks = h & 1;
    #pragma unroll
    for (int i = 0; i < 2; i++){
      int cc = wv*2 + i;
      if (cc < 4){
        int row = cc*8 + (lane>>3), slot = lane & 7;
        gl_lds16(k_t + ((size_t)bh*1024 + h*32 + row)*64 + ((slot ^ (row&7))*8),
                 (char*)Kh + db*4096 + cc*1024);
      } else {
        gl_lds16(v_t + ((size_t)bh*16 + t64)*4096 + ks*2048 + (cc-4)*512 + lane*8,
                 (char*)Vh + db*4096 + (cc-4)*1024);
      }
    }
  };

  auto COMPUTE = [&](int db){
    const char* Kb = (const char*)Kh + db*4096;
    const char* Vb = (const char*)Vh + db*4096;
    f32x4 scl[2][2] = {};
    #pragma unroll
    for (int jl = 0; jl < 2; jl++){
      int row = jl*16 + l15;
      int swz = (row&7)<<4;
      bf16x8 kf0 = *(const bf16x8*)(Kb + row*128 + ((g*16) ^ swz));
      bf16x8 kf1 = *(const bf16x8*)(Kb + row*128 + ((64 + g*16) ^ swz));
      __builtin_amdgcn_s_setprio(1);
      #pragma unroll
      for (int qt = 0; qt < 2; qt++){
        scl[qt][jl] = __builtin_amdgcn_mfma_f32_16x16x32_bf16(kf0, qf[qt][0], scl[qt][jl], 0, 0, 0);
        scl[qt][jl] = __builtin_amdgcn_mfma_f32_16x16x32_bf16(kf1, qf[qt][1], scl[qt][jl], 0, 0, 0);
      }
      __builtin_amdgcn_s_setprio(0);
    }
    bf16x8 pa[2];
    #pragma unroll
    for (int qt = 0; qt < 2; qt++){
      #pragma unroll
      for (int i2 = 0; i2 < 8; i2++)
        pa[qt][i2] = (__bf16)exp2_fast(scl[qt][i2>>2][i2&3]);
      osum[qt] = __builtin_amdgcn_mfma_f32_16x16x32_bf16(pa[qt], onesb, osum[qt], 0, 0, 0);
    }
    #pragma unroll
    for (int jd = 0; jd < 4; jd++){
      bf16x8 vbb = *(const bf16x8*)(Vb + (g*4+jd)*256 + l15*16);
      __builtin_amdgcn_s_setprio(1);
      #pragma unroll
      for (int qt = 0; qt < 2; qt++)
        o[qt][jd] = __builtin_amdgcn_mfma_f32_16x16x32_bf16(pa[qt], vbb, o[qt][jd], 0, 0, 0);
      __builtin_amdgcn_s_setprio(0);
    }
  };

  STAGE(0, 0);
  STAGE(1, 1);
  #pragma unroll 2
  for (int h = 0; h < 30; h++){
    STAGE((h+2)&3, h+2);
    asm volatile("s_waitcnt vmcnt(4)" ::: "memory");
    __builtin_amdgcn_s_barrier();
    __builtin_amdgcn_sched_barrier(0);    // pin: no ds_read hoists above the barrier
    COMPUTE(h&3);
  }
  asm volatile("s_waitcnt vmcnt(2)" ::: "memory");
  __builtin_amdgcn_s_barrier();
  __builtin_amdgcn_sched_barrier(0);
  COMPUTE(2);
  asm volatile("s_waitcnt vmcnt(0)" ::: "memory");
  __builtin_amdgcn_s_barrier();
  __builtin_amdgcn_sched_barrier(0);
  COMPUTE(3);

  #pragma unroll
  for (int qt = 0; qt < 2; qt++){
    #pragma unroll
    for (int r = 0; r < 4; r++){
      float inv = 1.f / osum[qt][r];
      int qrow = qb*128 + qt*64 + wv*16 + g*4 + r;
      #pragma unroll
      for (int jd = 0; jd < 4; jd++)
        a_bt[((size_t)bb*1024 + qrow)*512 + hh*64 + jd*16 + l15] = f2bf(o[qt][jd][r] * inv);
    }
  }
}

// ---------------- launch ----------------
extern "C" void kernel_launch(void* const* d_in, const int* in_sizes, int n_in,
                              void* d_out, int out_size, void* d_ws, size_t ws_size,
                              hipStream_t stream){
  const float* x  = (const float*)d_in[0];
  const float* nw = (const float*)d_in[1];
  const float* nb = (const float*)d_in[2];
  const float* qw = (const float*)d_in[3];
  const float* qb = (const float*)d_in[4];
  const float* pw = (const float*)d_in[5];
  const float* pb = (const float*)d_in[6];
  float* outp = (float*)d_out;

  char* ws = (char*)d_ws;
  short* hid  = (short*)(ws);               // 16.78 MB (reused as a_bt)
  short* qwb  = (short*)(ws + 16777216);    // permuted rows
  short* pwb  = (short*)(ws + 18350080);
  short* q_t  = (short*)(ws + 18874368);    // q[t][c], pre-scaled by 2^-3*log2e
  short* k_t  = (short*)(ws + 35651584);    // k[t][c]
  short* v_t  = (short*)(ws + 52428800);    // v in attn-tile cell layout
  short* a_bt = hid;
  float* qbp  = (float*)d_out;              // permuted bias scratch (d_out dead until gemmP)
  if (ws_size < 69206016) return;

  k_pre<<<4615, 256, 0, stream>>>(x, nw, nb, hid, qw, pw, qb, qwb, pwb, qbp);
  k_gemmQ<<<768, 256, 0, stream>>>(qwb, hid, qbp, q_t, k_t, v_t);
  k_attn<<<1024, 256, 0, stream>>>(q_t, k_t, v_t, a_bt);
  k_gemmP<<<512, 256, 0, stream>>>(pwb, a_bt, pb, x, outp);
}

// Round 14
// 119.582 us; speedup vs baseline: 1.1387x; 1.1387x over previous
//
#include <hip/hip_runtime.h>
#include <hip/hip_bf16.h>
#include <stdint.h>

// Shapes (fixed): B=16, C=512, L=1024, H=8, ch=64, groups=32

using f32x4  = __attribute__((ext_vector_type(4))) float;
using bf16x8 = __attribute__((ext_vector_type(8))) __bf16;
using s8v    = __attribute__((ext_vector_type(8))) short;
using s4v    = __attribute__((ext_vector_type(4))) short;

__device__ __forceinline__ short f2bf(float f){
  union { float f; unsigned u; } c; c.f = f;
  unsigned r = (c.u + 0x7FFFu + ((c.u >> 16) & 1u)) >> 16;   // RNE
  return (short)r;
}

__device__ __forceinline__ float exp2_fast(float x){
#if __has_builtin(__builtin_amdgcn_exp2f)
  return __builtin_amdgcn_exp2f(x);
#else
  return exp2f(x);
#endif
}

// async global->LDS, 16B per lane
__device__ __forceinline__ void gl_lds16(const void* g, void* l){
  __builtin_amdgcn_global_load_lds((const __attribute__((address_space(1))) void*)g,
                                   (__attribute__((address_space(3))) void*)l, 16, 0, 0);
}

// ---------------- fused: GroupNorm (blocks 0..511) + weight convert (blocks 512+) ----------------
__global__ __launch_bounds__(256) void k_pre(const float* __restrict__ x,
                                             const float* __restrict__ w,
                                             const float* __restrict__ bia,
                                             short* __restrict__ hid,
                                             const float* __restrict__ qw,
                                             const float* __restrict__ pw,
                                             const float* __restrict__ qb,
                                             short* __restrict__ qwb,
                                             short* __restrict__ pwb,
                                             float* __restrict__ qbp){
  int bid = blockIdx.x;
  int tid = threadIdx.x;
  if (bid >= 512){
    int i = (bid - 512) * 256 + tid;
    if (i < 786432){
      int o = i >> 9, kk = i & 511;
      int h = o / 192, rem = o - h*192;
      int nr = (rem >> 6)*512 + h*64 + (rem & 63);   // q|k|v row blocks
      qwb[nr*512 + kk] = f2bf(qw[i]);
    } else if (i < 1048576){
      int j = i - 786432;
      pwb[j] = f2bf(pw[j]);
    } else if (i < 1050112){
      int o = i - 1048576;
      int h = o / 192, rem = o - h*192;
      qbp[(rem >> 6)*512 + h*64 + (rem & 63)] = qb[o];
    }
    return;
  }
  int b = bid >> 5;
  int g = bid & 31;
  const float* xg = x + ((size_t)b*512 + g*16)*1024;
  int l0 = tid * 4;
  float v[16][4];
  float s1 = 0.f, s2 = 0.f;
  #pragma unroll
  for (int c = 0; c < 16; c++){
    f32x4 t = *(const f32x4*)(xg + c*1024 + l0);
    #pragma unroll
    for (int j = 0; j < 4; j++){ v[c][j] = t[j]; s1 += t[j]; s2 += t[j]*t[j]; }
  }
  #pragma unroll
  for (int m = 32; m; m >>= 1){ s1 += __shfl_xor(s1, m); s2 += __shfl_xor(s2, m); }
  __shared__ float r1[4], r2[4];
  int wv = tid >> 6, ln = tid & 63;
  if (ln == 0){ r1[wv] = s1; r2[wv] = s2; }
  __syncthreads();
  s1 = r1[0]+r1[1]+r1[2]+r1[3];
  s2 = r2[0]+r2[1]+r2[2]+r2[3];
  float mu = s1 * (1.f/16384.f);
  float var = s2 * (1.f/16384.f) - mu*mu;
  float rs = rsqrtf(var + 1e-5f);
  float ww[16], bb[16];
  #pragma unroll
  for (int c = 0; c < 16; c++){ ww[c] = w[g*16+c]*rs; bb[c] = bia[g*16+c]; }
  #pragma unroll
  for (int j = 0; j < 4; j++){
    short o[16];
    #pragma unroll
    for (int c = 0; c < 16; c++) o[c] = f2bf((v[c][j]-mu)*ww[c] + bb[c]);
    short* dst = hid + ((size_t)(b*1024 + l0 + j))*512 + g*16;
    *(s8v*)dst     = *(s8v*)o;
    *(s8v*)(dst+8) = *(s8v*)(o+8);
  }
}

// ---------------- QKV GEMM (R12-proven): 128x128 tile, BK=64, 2-buf, __syncthreads/iter ----------------
// v_t cell layout per (bh, s>>6) region of 4096 shorts (16B-contiguous PV frags):
//   idx = (((ks*4+gq)*4 + (c>>4))*16 + (c&15))*8 + (sl&3) + 4*((sl>>4)&1)
__global__ __launch_bounds__(256) void k_gemmQ(
    const short* __restrict__ A, const short* __restrict__ Bm,
    const float* __restrict__ bias,
    short* __restrict__ q_t, short* __restrict__ k_t, short* __restrict__ v_t)
{
  __shared__ short Al[2][128*64];
  __shared__ short Bl[2][128*64];
  int id = blockIdx.x;
  int xcd = id & 7, ix = id >> 3;
  int mt = ix % 12, nt = ix / 12;           // 192 per xcd: 12 m x 16 n
  int m0 = mt * 128;
  int n0 = (xcd + 8*nt) * 128;
  int tid = threadIdx.x;
  int lane = tid & 63;
  int wv = tid >> 6;
  int wr = wv >> 1, wc = wv & 1;
  int l15 = lane & 15, g = lane >> 4;
  f32x4 acc[4][4] = {};

  auto STAGE = [&](int db, int t){
    int k0 = t * 64;
    #pragma unroll
    for (int i = 0; i < 8; i++){
      int cc = wv*8 + i;                   // 32 chunks of 1KB (16 A + 16 B)
      if (cc < 16){
        int slot = cc*64 + lane;
        int row = slot >> 3, off = slot & 7;
        gl_lds16(A + (size_t)(m0+row)*512 + k0 + (off ^ (row&7))*8,
                 (char*)Al[db] + cc*1024);
      } else {
        int slot = (cc-16)*64 + lane;
        int row = slot >> 3, off = slot & 7;
        gl_lds16(Bm + (size_t)(n0+row)*512 + k0 + (off ^ (row&7))*8,
                 (char*)Bl[db] + (cc-16)*1024);
      }
    }
  };

  auto COMPUTE = [&](int db){
    #pragma unroll
    for (int kk = 0; kk < 2; kk++){
      bf16x8 af[4], bf[4];
      #pragma unroll
      for (int m = 0; m < 4; m++){
        int row = wr*64 + m*16 + l15;
        int byte = row*128 + (((kk*64) + (g*16)) ^ ((row&7)<<4));
        af[m] = *(const bf16x8*)((char*)Al[db] + byte);
      }
      #pragma unroll
      for (int n = 0; n < 4; n++){
        int row = wc*64 + n*16 + l15;
        int byte = row*128 + (((kk*64) + (g*16)) ^ ((row&7)<<4));
        bf[n] = *(const bf16x8*)((char*)Bl[db] + byte);
      }
      __builtin_amdgcn_s_setprio(1);
      #pragma unroll
      for (int m = 0; m < 4; m++)
        #pragma unroll
        for (int n = 0; n < 4; n++)
          acc[m][n] = __builtin_amdgcn_mfma_f32_16x16x32_bf16(af[m], bf[n], acc[m][n], 0, 0, 0);
      __builtin_amdgcn_s_setprio(0);
    }
  };

  STAGE(0, 0);
  for (int t = 0; t < 8; t++){
    __syncthreads();                 // full fence+barrier (race-sealed)
    if (t < 7) STAGE((t+1)&1, t+1);
    COMPUTE(t&1);
  }
  __syncthreads();                   // epilogue may reuse LDS as scratch

  int sel = m0 >> 9;               // 0=q, 1=k, 2=v (block-uniform)
  if (sel < 2){
    const float sc = (sel == 0) ? 0.18033688011112042f : 1.0f;  // 2^-3 * log2(e) folded into q
    short* dstb = (sel == 0) ? q_t : k_t;
    #pragma unroll
    for (int m = 0; m < 4; m++){
      int ob = m0 + wr*64 + m*16 + (g<<2);
      int hh = (ob>>6)&7, c0 = ob&63;
      float bs[4];
      #pragma unroll
      for (int r = 0; r < 4; r++) bs[r] = bias[ob+r];
      #pragma unroll
      for (int n = 0; n < 4; n++){
        int nn = n0 + wc*64 + n*16 + l15;
        int bb = nn >> 10, ll = nn & 1023;
        int bh = bb*8 + hh;
        short o4[4];
        #pragma unroll
        for (int r = 0; r < 4; r++) o4[r] = f2bf((acc[m][n][r] + bs[r]) * sc);
        *(s4v*)(dstb + ((size_t)bh*1024 + ll)*64 + c0) = *(s4v*)o4;
      }
    }
  } else {
    // v tile: repack through LDS (32KB = 2 heads x 2 s-regions), then 16B copy-out
    short* Sc = (short*)Al;
    #pragma unroll
    for (int m = 0; m < 4; m++){
      int ob = m0 + wr*64 + m*16 + (g<<2);
      int h2 = (ob>>6)&1, cq = (ob>>4)&3;
      float bs[4];
      #pragma unroll
      for (int r = 0; r < 4; r++) bs[r] = bias[ob+r];
      #pragma unroll
      for (int n = 0; n < 4; n++){
        int nn = n0 + wc*64 + n*16 + l15;
        int sl = nn & 63, sreg = (nn>>6)&1;
        int ks2 = sl >> 5, gq = (sl>>2)&3, i2 = (sl&3) + 4*((sl>>4)&1);
        int base = (h2*2 + sreg)*4096 + (((ks2*4+gq)*4 + cq)*16 + (g<<2))*8 + i2;
        #pragma unroll
        for (int r = 0; r < 4; r++)
          Sc[base + r*8] = f2bf(acc[m][n][r] + bs[r]);
      }
    }
    __syncthreads();
    int b0  = n0 >> 10;
    int s64 = (n0 >> 6) & 15;
    int hb  = (m0 - 1024) >> 6;      // head base (0,2,4,6)
    #pragma unroll
    for (int it = 0; it < 8; it++){
      int flat = it*2048 + tid*8;
      int h2 = flat >> 13, rem = flat & 8191, sreg = rem >> 12, off = rem & 4095;
      int bh = b0*8 + hb + h2;
      *(s8v*)(v_t + ((size_t)bh*16 + s64 + sreg)*4096 + off) = *(const s8v*)(Sc + flat);
    }
  }
}

// ---------------- Proj GEMM (R12-proven): 128x128, BK=64, 2-buf, __syncthreads ----------------
__global__ __launch_bounds__(256) void k_gemmP(
    const short* __restrict__ A, const short* __restrict__ Bm,
    const float* __restrict__ bias, const float* __restrict__ xres,
    float* __restrict__ outp)
{
  __shared__ short Al[2][128*64];
  __shared__ short Bl[2][128*64];
  int id = blockIdx.x;
  int xcd = id & 7, ix = id >> 3;
  int mt = ix & 3, nt = ix >> 2;
  int m0 = mt * 128;
  int n0 = (xcd + 8*nt) * 128;
  int tid = threadIdx.x;
  int lane = tid & 63;
  int wv = tid >> 6;
  int wr = wv >> 1, wc = wv & 1;
  int l15 = lane & 15, g = lane >> 4;
  f32x4 acc[4][4] = {};

  auto STAGE = [&](int db, int t){
    int k0 = t * 64;
    #pragma unroll
    for (int i = 0; i < 8; i++){
      int cc = wv*8 + i;
      if (cc < 16){
        int slot = cc*64 + lane;
        int row = slot >> 3, off = slot & 7;
        gl_lds16(A + (size_t)(m0+row)*512 + k0 + (off ^ (row&7))*8,
                 (char*)Al[db] + cc*1024);
      } else {
        int slot = (cc-16)*64 + lane;
        int row = slot >> 3, off = slot & 7;
        gl_lds16(Bm + (size_t)(n0+row)*512 + k0 + (off ^ (row&7))*8,
                 (char*)Bl[db] + (cc-16)*1024);
      }
    }
  };

  auto COMPUTE = [&](int db){
    #pragma unroll
    for (int kk = 0; kk < 2; kk++){
      bf16x8 af[4], bf[4];
      #pragma unroll
      for (int m = 0; m < 4; m++){
        int row = wr*64 + m*16 + l15;
        int byte = row*128 + (((kk*64) + (g*16)) ^ ((row&7)<<4));
        af[m] = *(const bf16x8*)((char*)Al[db] + byte);
      }
      #pragma unroll
      for (int n = 0; n < 4; n++){
        int row = wc*64 + n*16 + l15;
        int byte = row*128 + (((kk*64) + (g*16)) ^ ((row&7)<<4));
        bf[n] = *(const bf16x8*)((char*)Bl[db] + byte);
      }
      __builtin_amdgcn_s_setprio(1);
      #pragma unroll
      for (int m = 0; m < 4; m++)
        #pragma unroll
        for (int n = 0; n < 4; n++)
          acc[m][n] = __builtin_amdgcn_mfma_f32_16x16x32_bf16(af[m], bf[n], acc[m][n], 0, 0, 0);
      __builtin_amdgcn_s_setprio(0);
    }
  };

  STAGE(0, 0);
  for (int t = 0; t < 8; t++){
    __syncthreads();
    if (t < 7) STAGE((t+1)&1, t+1);
    COMPUTE(t&1);
  }

  #pragma unroll
  for (int m = 0; m < 4; m++){
    int ob = m0 + wr*64 + m*16 + (g<<2);
    float bs[4];
    #pragma unroll
    for (int r = 0; r < 4; r++) bs[r] = bias[ob+r];
    #pragma unroll
    for (int n = 0; n < 4; n++){
      int nn = n0 + wc*64 + n*16 + l15;
      int bb = nn >> 10, ll = nn & 1023;
      #pragma unroll
      for (int r = 0; r < 4; r++){
        size_t idx = ((size_t)bb*512 + ob + r)*1024 + ll;
        outp[idx] = xres[idx] + acc[m][n][r] + bs[r];
      }
    }
  }
}

// ---------------- Flash attention: counted-vmcnt pipeline, qt=4 (64 q-rows/wave) ----------------
// Per K/V ds_read now feeds 4 MFMA (2x fragment reuse vs R12). Grid 512, 2 blocks/CU.
__global__ __launch_bounds__(256, 2) void k_attn(
    const short* __restrict__ q_t, const short* __restrict__ k_t,
    const short* __restrict__ v_t, short* __restrict__ a_bt)
{
  __shared__ short Kh[4*2048];
  __shared__ short Vh[4*2048];
  int id = blockIdx.x;                 // 512
  int xcd = id & 7, ix = id >> 3;      // 64 per xcd
  int bh = xcd*16 + (ix >> 2);
  int qb = ix & 3;                     // 256 q-rows per WG
  int bb = bh >> 3, hh = bh & 7;
  int tid = threadIdx.x;
  int lane = tid & 63;
  int wv = tid >> 6;
  int l15 = lane & 15, g = lane >> 4;

  bf16x8 qf[4][2];
  #pragma unroll
  for (int qt = 0; qt < 4; qt++){
    const short* qbase = q_t + ((size_t)bh*1024 + qb*256 + qt*64 + wv*16 + l15)*64 + g*8;
    qf[qt][0] = *(const bf16x8*)(qbase);
    qf[qt][1] = *(const bf16x8*)(qbase + 32);
  }
  asm volatile("" :: "v"(qf[0][0]), "v"(qf[0][1]), "v"(qf[1][0]), "v"(qf[1][1]),
                     "v"(qf[2][0]), "v"(qf[2][1]), "v"(qf[3][0]), "v"(qf[3][1]));

  bf16x8 onesb;
  #pragma unroll
  for (int i = 0; i < 8; i++) onesb[i] = (__bf16)1.0f;

  f32x4 o[4][4] = {};
  f32x4 osum[4] = {};

  auto STAGE = [&](int db, int h){
    int t64 = h >> 1, ks = h & 1;
    #pragma unroll
    for (int i = 0; i < 2; i++){
      int cc = wv*2 + i;
      if (cc < 4){
        int row = cc*8 + (lane>>3), slot = lane & 7;
        gl_lds16(k_t + ((size_t)bh*1024 + h*32 + row)*64 + ((slot ^ (row&7))*8),
                 (char*)Kh + db*4096 + cc*1024);
      } else {
        gl_lds16(v_t + ((size_t)bh*16 + t64)*4096 + ks*2048 + (cc-4)*512 + lane*8,
                 (char*)Vh + db*4096 + (cc-4)*1024);
      }
    }
  };

  auto COMPUTE = [&](int db){
    const char* Kb = (const char*)Kh + db*4096;
    const char* Vb = (const char*)Vh + db*4096;
    f32x4 scl[4][2] = {};
    #pragma unroll
    for (int jl = 0; jl < 2; jl++){
      int row = jl*16 + l15;
      int swz = (row&7)<<4;
      bf16x8 kf0 = *(const bf16x8*)(Kb + row*128 + ((g*16) ^ swz));
      bf16x8 kf1 = *(const bf16x8*)(Kb + row*128 + ((64 + g*16) ^ swz));
      __builtin_amdgcn_s_setprio(1);
      #pragma unroll
      for (int qt = 0; qt < 4; qt++){
        scl[qt][jl] = __builtin_amdgcn_mfma_f32_16x16x32_bf16(kf0, qf[qt][0], scl[qt][jl], 0, 0, 0);
        scl[qt][jl] = __builtin_amdgcn_mfma_f32_16x16x32_bf16(kf1, qf[qt][1], scl[qt][jl], 0, 0, 0);
      }
      __builtin_amdgcn_s_setprio(0);
    }
    bf16x8 pa[4];
    #pragma unroll
    for (int qt = 0; qt < 4; qt++){
      #pragma unroll
      for (int i2 = 0; i2 < 8; i2++)
        pa[qt][i2] = (__bf16)exp2_fast(scl[qt][i2>>2][i2&3]);
      osum[qt] = __builtin_amdgcn_mfma_f32_16x16x32_bf16(pa[qt], onesb, osum[qt], 0, 0, 0);
    }
    #pragma unroll
    for (int jd = 0; jd < 4; jd++){
      bf16x8 vbb = *(const bf16x8*)(Vb + (g*4+jd)*256 + l15*16);
      __builtin_amdgcn_s_setprio(1);
      #pragma unroll
      for (int qt = 0; qt < 4; qt++)
        o[qt][jd] = __builtin_amdgcn_mfma_f32_16x16x32_bf16(pa[qt], vbb, o[qt][jd], 0, 0, 0);
      __builtin_amdgcn_s_setprio(0);
    }
  };

  STAGE(0, 0);
  STAGE(1, 1);
  for (int h = 0; h < 30; h++){
    STAGE((h+2)&3, h+2);
    asm volatile("s_waitcnt vmcnt(4)" ::: "memory");
    __builtin_amdgcn_s_barrier();
    __builtin_amdgcn_sched_barrier(0);    // pin: no ds_read hoists above the barrier
    COMPUTE(h&3);
  }
  asm volatile("s_waitcnt vmcnt(2)" ::: "memory");
  __builtin_amdgcn_s_barrier();
  __builtin_amdgcn_sched_barrier(0);
  COMPUTE(2);
  asm volatile("s_waitcnt vmcnt(0)" ::: "memory");
  __builtin_amdgcn_s_barrier();
  __builtin_amdgcn_sched_barrier(0);
  COMPUTE(3);

  #pragma unroll
  for (int qt = 0; qt < 4; qt++){
    #pragma unroll
    for (int r = 0; r < 4; r++){
      float inv = 1.f / osum[qt][r];
      int qrow = qb*256 + qt*64 + wv*16 + g*4 + r;
      #pragma unroll
      for (int jd = 0; jd < 4; jd++)
        a_bt[((size_t)bb*1024 + qrow)*512 + hh*64 + jd*16 + l15] = f2bf(o[qt][jd][r] * inv);
    }
  }
}

// ---------------- launch ----------------
extern "C" void kernel_launch(void* const* d_in, const int* in_sizes, int n_in,
                              void* d_out, int out_size, void* d_ws, size_t ws_size,
                              hipStream_t stream){
  const float* x  = (const float*)d_in[0];
  const float* nw = (const float*)d_in[1];
  const float* nb = (const float*)d_in[2];
  const float* qw = (const float*)d_in[3];
  const float* qb = (const float*)d_in[4];
  const float* pw = (const float*)d_in[5];
  const float* pb = (const float*)d_in[6];
  float* outp = (float*)d_out;

  char* ws = (char*)d_ws;
  short* hid  = (short*)(ws);               // 16.78 MB (reused as a_bt)
  short* qwb  = (short*)(ws + 16777216);    // permuted rows
  short* pwb  = (short*)(ws + 18350080);
  short* q_t  = (short*)(ws + 18874368);    // q[t][c], pre-scaled by 2^-3*log2e
  short* k_t  = (short*)(ws + 35651584);    // k[t][c]
  short* v_t  = (short*)(ws + 52428800);    // v in attn-tile cell layout
  short* a_bt = hid;
  float* qbp  = (float*)d_out;              // permuted bias scratch (d_out dead until gemmP)
  if (ws_size < 69206016) return;

  k_pre<<<4615, 256, 0, stream>>>(x, nw, nb, hid, qw, pw, qb, qwb, pwb, qbp);
  k_gemmQ<<<1536, 256, 0, stream>>>(qwb, hid, qbp, q_t, k_t, v_t);
  k_attn<<<512, 256, 0, stream>>>(q_t, k_t, v_t, a_bt);
  k_gemmP<<<512, 256, 0, stream>>>(pwb, a_bt, pb, x, outp);
}

// Round 15
// 115.036 us; speedup vs baseline: 1.1837x; 1.0395x over previous
//
#include <hip/hip_runtime.h>
#include <hip/hip_bf16.h>
#include <stdint.h>

// Shapes (fixed): B=16, C=512, L=1024, H=8, ch=64, groups=32

using f32x4  = __attribute__((ext_vector_type(4))) float;
using bf16x8 = __attribute__((ext_vector_type(8))) __bf16;
using s8v    = __attribute__((ext_vector_type(8))) short;
using s4v    = __attribute__((ext_vector_type(4))) short;

__device__ __forceinline__ short f2bf(float f){
  union { float f; unsigned u; } c; c.f = f;
  unsigned r = (c.u + 0x7FFFu + ((c.u >> 16) & 1u)) >> 16;   // RNE
  return (short)r;
}

__device__ __forceinline__ float exp2_fast(float x){
#if __has_builtin(__builtin_amdgcn_exp2f)
  return __builtin_amdgcn_exp2f(x);
#else
  return exp2f(x);
#endif
}

// async global->LDS, 16B per lane
__device__ __forceinline__ void gl_lds16(const void* g, void* l){
  __builtin_amdgcn_global_load_lds((const __attribute__((address_space(1))) void*)g,
                                   (__attribute__((address_space(3))) void*)l, 16, 0, 0);
}

// ---------------- fused: GroupNorm (blocks 0..511) + weight convert (blocks 512+) ----------------
__global__ __launch_bounds__(256) void k_pre(const float* __restrict__ x,
                                             const float* __restrict__ w,
                                             const float* __restrict__ bia,
                                             short* __restrict__ hid,
                                             const float* __restrict__ qw,
                                             const float* __restrict__ pw,
                                             const float* __restrict__ qb,
                                             short* __restrict__ qwb,
                                             short* __restrict__ pwb,
                                             float* __restrict__ qbp){
  int bid = blockIdx.x;
  int tid = threadIdx.x;
  if (bid >= 512){
    int i = (bid - 512) * 256 + tid;
    if (i < 786432){
      int o = i >> 9, kk = i & 511;
      int h = o / 192, rem = o - h*192;
      int nr = (rem >> 6)*512 + h*64 + (rem & 63);   // q|k|v row blocks
      qwb[nr*512 + kk] = f2bf(qw[i]);
    } else if (i < 1048576){
      int j = i - 786432;
      pwb[j] = f2bf(pw[j]);
    } else if (i < 1050112){
      int o = i - 1048576;
      int h = o / 192, rem = o - h*192;
      qbp[(rem >> 6)*512 + h*64 + (rem & 63)] = qb[o];
    }
    return;
  }
  int b = bid >> 5;
  int g = bid & 31;
  const float* xg = x + ((size_t)b*512 + g*16)*1024;
  int l0 = tid * 4;
  float v[16][4];
  float s1 = 0.f, s2 = 0.f;
  #pragma unroll
  for (int c = 0; c < 16; c++){
    f32x4 t = *(const f32x4*)(xg + c*1024 + l0);
    #pragma unroll
    for (int j = 0; j < 4; j++){ v[c][j] = t[j]; s1 += t[j]; s2 += t[j]*t[j]; }
  }
  #pragma unroll
  for (int m = 32; m; m >>= 1){ s1 += __shfl_xor(s1, m); s2 += __shfl_xor(s2, m); }
  __shared__ float r1[4], r2[4];
  int wv = tid >> 6, ln = tid & 63;
  if (ln == 0){ r1[wv] = s1; r2[wv] = s2; }
  __syncthreads();
  s1 = r1[0]+r1[1]+r1[2]+r1[3];
  s2 = r2[0]+r2[1]+r2[2]+r2[3];
  float mu = s1 * (1.f/16384.f);
  float var = s2 * (1.f/16384.f) - mu*mu;
  float rs = rsqrtf(var + 1e-5f);
  float ww[16], bb[16];
  #pragma unroll
  for (int c = 0; c < 16; c++){ ww[c] = w[g*16+c]*rs; bb[c] = bia[g*16+c]; }
  #pragma unroll
  for (int j = 0; j < 4; j++){
    short o[16];
    #pragma unroll
    for (int c = 0; c < 16; c++) o[c] = f2bf((v[c][j]-mu)*ww[c] + bb[c]);
    short* dst = hid + ((size_t)(b*1024 + l0 + j))*512 + g*16;
    *(s8v*)dst     = *(s8v*)o;
    *(s8v*)(dst+8) = *(s8v*)(o+8);
  }
}

// ---------------- QKV GEMM (R12 structure + hoisted stage pointers) ----------------
// v_t cell layout per (bh, s>>6) region of 4096 shorts (16B-contiguous PV frags):
//   idx = (((ks*4+gq)*4 + (c>>4))*16 + (c&15))*8 + (sl&3) + 4*((sl>>4)&1)
__global__ __launch_bounds__(256) void k_gemmQ(
    const short* __restrict__ A, const short* __restrict__ Bm,
    const float* __restrict__ bias,
    short* __restrict__ q_t, short* __restrict__ k_t, short* __restrict__ v_t)
{
  __shared__ short Al[2][128*64];
  __shared__ short Bl[2][128*64];
  int id = blockIdx.x;
  int xcd = id & 7, ix = id >> 3;
  int mt = ix % 12, nt = ix / 12;           // 192 per xcd: 12 m x 16 n
  int m0 = mt * 128;
  int n0 = (xcd + 8*nt) * 128;
  int tid = threadIdx.x;
  int lane = tid & 63;
  int wv = tid >> 6;
  int wr = wv >> 1, wc = wv & 1;
  int l15 = lane & 15, g = lane >> 4;
  f32x4 acc[4][4] = {};

  // hoisted per-lane stage pointers (deletes per-iter addr VALU)
  const short* srcp[8]; char* dstp[8];
  #pragma unroll
  for (int i = 0; i < 8; i++){
    int cc = wv*8 + i;
    if (cc < 16){
      int slot = cc*64 + lane;
      int row = slot >> 3, off = slot & 7;
      srcp[i] = A + (size_t)(m0+row)*512 + (off ^ (row&7))*8;
      dstp[i] = (char*)Al[0] + cc*1024;
    } else {
      int slot = (cc-16)*64 + lane;
      int row = slot >> 3, off = slot & 7;
      srcp[i] = Bm + (size_t)(n0+row)*512 + (off ^ (row&7))*8;
      dstp[i] = (char*)Bl[0] + (cc-16)*1024;
    }
  }

  auto STAGE = [&](int db, int t){
    #pragma unroll
    for (int i = 0; i < 8; i++)
      gl_lds16(srcp[i] + t*64, dstp[i] + db*16384);
  };

  auto COMPUTE = [&](int db){
    #pragma unroll
    for (int kk = 0; kk < 2; kk++){
      bf16x8 af[4], bf[4];
      #pragma unroll
      for (int m = 0; m < 4; m++){
        int row = wr*64 + m*16 + l15;
        int byte = row*128 + (((kk*64) + (g*16)) ^ ((row&7)<<4));
        af[m] = *(const bf16x8*)((char*)Al[db] + byte);
      }
      #pragma unroll
      for (int n = 0; n < 4; n++){
        int row = wc*64 + n*16 + l15;
        int byte = row*128 + (((kk*64) + (g*16)) ^ ((row&7)<<4));
        bf[n] = *(const bf16x8*)((char*)Bl[db] + byte);
      }
      __builtin_amdgcn_s_setprio(1);
      #pragma unroll
      for (int m = 0; m < 4; m++)
        #pragma unroll
        for (int n = 0; n < 4; n++)
          acc[m][n] = __builtin_amdgcn_mfma_f32_16x16x32_bf16(af[m], bf[n], acc[m][n], 0, 0, 0);
      __builtin_amdgcn_s_setprio(0);
    }
  };

  STAGE(0, 0);
  for (int t = 0; t < 8; t++){
    __syncthreads();                 // full fence+barrier (race-sealed)
    if (t < 7) STAGE((t+1)&1, t+1);
    COMPUTE(t&1);
  }
  __syncthreads();                   // epilogue may reuse LDS as scratch

  int sel = m0 >> 9;               // 0=q, 1=k, 2=v (block-uniform)
  if (sel < 2){
    const float sc = (sel == 0) ? 0.18033688011112042f : 1.0f;  // 2^-3 * log2(e) folded into q
    short* dstb = (sel == 0) ? q_t : k_t;
    #pragma unroll
    for (int m = 0; m < 4; m++){
      int ob = m0 + wr*64 + m*16 + (g<<2);
      int hh = (ob>>6)&7, c0 = ob&63;
      float bs[4];
      #pragma unroll
      for (int r = 0; r < 4; r++) bs[r] = bias[ob+r];
      #pragma unroll
      for (int n = 0; n < 4; n++){
        int nn = n0 + wc*64 + n*16 + l15;
        int bb = nn >> 10, ll = nn & 1023;
        int bh = bb*8 + hh;
        short o4[4];
        #pragma unroll
        for (int r = 0; r < 4; r++) o4[r] = f2bf((acc[m][n][r] + bs[r]) * sc);
        *(s4v*)(dstb + ((size_t)bh*1024 + ll)*64 + c0) = *(s4v*)o4;
      }
    }
  } else {
    // v tile: repack through LDS (32KB = 2 heads x 2 s-regions), then 16B copy-out
    short* Sc = (short*)Al;
    #pragma unroll
    for (int m = 0; m < 4; m++){
      int ob = m0 + wr*64 + m*16 + (g<<2);
      int h2 = (ob>>6)&1, cq = (ob>>4)&3;
      float bs[4];
      #pragma unroll
      for (int r = 0; r < 4; r++) bs[r] = bias[ob+r];
      #pragma unroll
      for (int n = 0; n < 4; n++){
        int nn = n0 + wc*64 + n*16 + l15;
        int sl = nn & 63, sreg = (nn>>6)&1;
        int ks2 = sl >> 5, gq = (sl>>2)&3, i2 = (sl&3) + 4*((sl>>4)&1);
        int base = (h2*2 + sreg)*4096 + (((ks2*4+gq)*4 + cq)*16 + (g<<2))*8 + i2;
        #pragma unroll
        for (int r = 0; r < 4; r++)
          Sc[base + r*8] = f2bf(acc[m][n][r] + bs[r]);
      }
    }
    __syncthreads();
    int b0  = n0 >> 10;
    int s64 = (n0 >> 6) & 15;
    int hb  = (m0 - 1024) >> 6;      // head base (0,2,4,6)
    #pragma unroll
    for (int it = 0; it < 8; it++){
      int flat = it*2048 + tid*8;
      int h2 = flat >> 13, rem = flat & 8191, sreg = rem >> 12, off = rem & 4095;
      int bh = b0*8 + hb + h2;
      *(s8v*)(v_t + ((size_t)bh*16 + s64 + sreg)*4096 + off) = *(const s8v*)(Sc + flat);
    }
  }
}

// ---------------- Proj GEMM (R12 structure + hoisted stage pointers) ----------------
__global__ __launch_bounds__(256) void k_gemmP(
    const short* __restrict__ A, const short* __restrict__ Bm,
    const float* __restrict__ bias, const float* __restrict__ xres,
    float* __restrict__ outp)
{
  __shared__ short Al[2][128*64];
  __shared__ short Bl[2][128*64];
  int id = blockIdx.x;
  int xcd = id & 7, ix = id >> 3;
  int mt = ix & 3, nt = ix >> 2;
  int m0 = mt * 128;
  int n0 = (xcd + 8*nt) * 128;
  int tid = threadIdx.x;
  int lane = tid & 63;
  int wv = tid >> 6;
  int wr = wv >> 1, wc = wv & 1;
  int l15 = lane & 15, g = lane >> 4;
  f32x4 acc[4][4] = {};

  const short* srcp[8]; char* dstp[8];
  #pragma unroll
  for (int i = 0; i < 8; i++){
    int cc = wv*8 + i;
    if (cc < 16){
      int slot = cc*64 + lane;
      int row = slot >> 3, off = slot & 7;
      srcp[i] = A + (size_t)(m0+row)*512 + (off ^ (row&7))*8;
      dstp[i] = (char*)Al[0] + cc*1024;
    } else {
      int slot = (cc-16)*64 + lane;
      int row = slot >> 3, off = slot & 7;
      srcp[i] = Bm + (size_t)(n0+row)*512 + (off ^ (row&7))*8;
      dstp[i] = (char*)Bl[0] + (cc-16)*1024;
    }
  }

  auto STAGE = [&](int db, int t){
    #pragma unroll
    for (int i = 0; i < 8; i++)
      gl_lds16(srcp[i] + t*64, dstp[i] + db*16384);
  };

  auto COMPUTE = [&](int db){
    #pragma unroll
    for (int kk = 0; kk < 2; kk++){
      bf16x8 af[4], bf[4];
      #pragma unroll
      for (int m = 0; m < 4; m++){
        int row = wr*64 + m*16 + l15;
        int byte = row*128 + (((kk*64) + (g*16)) ^ ((row&7)<<4));
        af[m] = *(const bf16x8*)((char*)Al[db] + byte);
      }
      #pragma unroll
      for (int n = 0; n < 4; n++){
        int row = wc*64 + n*16 + l15;
        int byte = row*128 + (((kk*64) + (g*16)) ^ ((row&7)<<4));
        bf[n] = *(const bf16x8*)((char*)Bl[db] + byte);
      }
      __builtin_amdgcn_s_setprio(1);
      #pragma unroll
      for (int m = 0; m < 4; m++)
        #pragma unroll
        for (int n = 0; n < 4; n++)
          acc[m][n] = __builtin_amdgcn_mfma_f32_16x16x32_bf16(af[m], bf[n], acc[m][n], 0, 0, 0);
      __builtin_amdgcn_s_setprio(0);
    }
  };

  STAGE(0, 0);
  for (int t = 0; t < 8; t++){
    __syncthreads();
    if (t < 7) STAGE((t+1)&1, t+1);
    COMPUTE(t&1);
  }

  #pragma unroll
  for (int m = 0; m < 4; m++){
    int ob = m0 + wr*64 + m*16 + (g<<2);
    float bs[4];
    #pragma unroll
    for (int r = 0; r < 4; r++) bs[r] = bias[ob+r];
    #pragma unroll
    for (int n = 0; n < 4; n++){
      int nn = n0 + wc*64 + n*16 + l15;
      int bb = nn >> 10, ll = nn & 1023;
      #pragma unroll
      for (int r = 0; r < 4; r++){
        size_t idx = ((size_t)bb*512 + ob + r)*1024 + ll;
        outp[idx] = xres[idx] + acc[m][n][r] + bs[r];
      }
    }
  }
}

// ---------------- Flash attention: software-pipelined (QK(h+1) overlaps exp/PV(h)) ----------------
// qt=2, grid 1024, 4 blocks/CU. Two named scl sets (no runtime indexing), unroll-by-2.
__global__ __launch_bounds__(256, 4) void k_attn(
    const short* __restrict__ q_t, const short* __restrict__ k_t,
    const short* __restrict__ v_t, short* __restrict__ a_bt)
{
  __shared__ short Kh[4*2048];
  __shared__ short Vh[4*2048];
  int id = blockIdx.x;                 // 1024
  int xcd = id & 7, ix = id >> 3;
  int bh = xcd*16 + (ix >> 3);
  int qb = ix & 7;
  int bb = bh >> 3, hh = bh & 7;
  int tid = threadIdx.x;
  int lane = tid & 63;
  int wv = tid >> 6;
  int l15 = lane & 15, g = lane >> 4;

  bf16x8 qf[2][2];
  #pragma unroll
  for (int qt = 0; qt < 2; qt++){
    const short* qbase = q_t + ((size_t)bh*1024 + qb*128 + qt*64 + wv*16 + l15)*64 + g*8;
    qf[qt][0] = *(const bf16x8*)(qbase);
    qf[qt][1] = *(const bf16x8*)(qbase + 32);
  }
  asm volatile("" :: "v"(qf[0][0]), "v"(qf[0][1]), "v"(qf[1][0]), "v"(qf[1][1]));

  bf16x8 onesb;
  #pragma unroll
  for (int i = 0; i < 8; i++) onesb[i] = (__bf16)1.0f;

  f32x4 o[2][4] = {};
  f32x4 osum[2] = {};

  // hoisted per-lane stage pointers: src(h) = sp[i] + h*2048 shorts
  const short* sp[2]; char* dp[2];
  #pragma unroll
  for (int i = 0; i < 2; i++){
    int cc = wv*2 + i;
    if (cc < 4){
      int row = cc*8 + (lane>>3), slot = lane & 7;
      sp[i] = k_t + ((size_t)bh*1024 + row)*64 + (slot ^ (row&7))*8;
      dp[i] = (char*)Kh + cc*1024;
    } else {
      sp[i] = v_t + (size_t)bh*16*4096 + (cc-4)*512 + lane*8;
      dp[i] = (char*)Vh + (cc-4)*1024;
    }
  }
  auto STAGE = [&](int db, int h){
    #pragma unroll
    for (int i = 0; i < 2; i++)
      gl_lds16(sp[i] + h*2048, dp[i] + db*4096);
  };

  auto QK = [&](f32x4 (&scl)[2][2], int db){
    const char* Kb = (const char*)Kh + db*4096;
    #pragma unroll
    for (int qt = 0; qt < 2; qt++)
      #pragma unroll
      for (int jl = 0; jl < 2; jl++)
        scl[qt][jl] = f32x4{0.f, 0.f, 0.f, 0.f};
    #pragma unroll
    for (int jl = 0; jl < 2; jl++){
      int row = jl*16 + l15;
      int swz = (row&7)<<4;
      bf16x8 kf0 = *(const bf16x8*)(Kb + row*128 + ((g*16) ^ swz));
      bf16x8 kf1 = *(const bf16x8*)(Kb + row*128 + ((64 + g*16) ^ swz));
      __builtin_amdgcn_s_setprio(1);
      #pragma unroll
      for (int qt = 0; qt < 2; qt++){
        scl[qt][jl] = __builtin_amdgcn_mfma_f32_16x16x32_bf16(kf0, qf[qt][0], scl[qt][jl], 0, 0, 0);
        scl[qt][jl] = __builtin_amdgcn_mfma_f32_16x16x32_bf16(kf1, qf[qt][1], scl[qt][jl], 0, 0, 0);
      }
      __builtin_amdgcn_s_setprio(0);
    }
  };

  auto EXP_PV = [&](f32x4 (&scl)[2][2], int db){
    const char* Vb = (const char*)Vh + db*4096;
    bf16x8 pa[2];
    #pragma unroll
    for (int qt = 0; qt < 2; qt++){
      #pragma unroll
      for (int i2 = 0; i2 < 8; i2++)
        pa[qt][i2] = (__bf16)exp2_fast(scl[qt][i2>>2][i2&3]);
      osum[qt] = __builtin_amdgcn_mfma_f32_16x16x32_bf16(pa[qt], onesb, osum[qt], 0, 0, 0);
    }
    #pragma unroll
    for (int jd = 0; jd < 4; jd++){
      bf16x8 vbb = *(const bf16x8*)(Vb + (g*4+jd)*256 + l15*16);
      __builtin_amdgcn_s_setprio(1);
      #pragma unroll
      for (int qt = 0; qt < 2; qt++)
        o[qt][jd] = __builtin_amdgcn_mfma_f32_16x16x32_bf16(pa[qt], vbb, o[qt][jd], 0, 0, 0);
      __builtin_amdgcn_s_setprio(0);
    }
  };

  f32x4 sA[2][2], sB[2][2];

  STAGE(0, 0);
  STAGE(1, 1);
  asm volatile("s_waitcnt vmcnt(2)" ::: "memory");   // stage 0 landed
  __builtin_amdgcn_s_barrier();
  __builtin_amdgcn_sched_barrier(0);
  QK(sA, 0);
  for (int h = 0; h < 30; h += 2){
    STAGE((h+2)&3, h+2);
    asm volatile("s_waitcnt vmcnt(2)" ::: "memory"); // stage h+1 landed; h+2 in flight
    __builtin_amdgcn_s_barrier();
    __builtin_amdgcn_sched_barrier(0);
    QK(sB, (h+1)&3);
    EXP_PV(sA, h&3);
    STAGE((h+3)&3, h+3);
    asm volatile("s_waitcnt vmcnt(2)" ::: "memory"); // stage h+2 landed; h+3 in flight
    __builtin_amdgcn_s_barrier();
    __builtin_amdgcn_sched_barrier(0);
    QK(sA, (h+2)&3);
    EXP_PV(sB, (h+1)&3);
  }
  asm volatile("s_waitcnt vmcnt(0)" ::: "memory");   // stage 31 landed
  __builtin_amdgcn_s_barrier();
  __builtin_amdgcn_sched_barrier(0);
  QK(sB, 3);          // tile 31
  EXP_PV(sA, 2);      // tile 30
  EXP_PV(sB, 3);      // tile 31

  #pragma unroll
  for (int qt = 0; qt < 2; qt++){
    #pragma unroll
    for (int r = 0; r < 4; r++){
      float inv = 1.f / osum[qt][r];
      int qrow = qb*128 + qt*64 + wv*16 + g*4 + r;
      #pragma unroll
      for (int jd = 0; jd < 4; jd++)
        a_bt[((size_t)bb*1024 + qrow)*512 + hh*64 + jd*16 + l15] = f2bf(o[qt][jd][r] * inv);
    }
  }
}

// ---------------- launch ----------------
extern "C" void kernel_launch(void* const* d_in, const int* in_sizes, int n_in,
                              void* d_out, int out_size, void* d_ws, size_t ws_size,
                              hipStream_t stream){
  const float* x  = (const float*)d_in[0];
  const float* nw = (const float*)d_in[1];
  const float* nb = (const float*)d_in[2];
  const float* qw = (const float*)d_in[3];
  const float* qb = (const float*)d_in[4];
  const float* pw = (const float*)d_in[5];
  const float* pb = (const float*)d_in[6];
  float* outp = (float*)d_out;

  char* ws = (char*)d_ws;
  short* hid  = (short*)(ws);               // 16.78 MB (reused as a_bt)
  short* qwb  = (short*)(ws + 16777216);    // permuted rows
  short* pwb  = (short*)(ws + 18350080);
  short* q_t  = (short*)(ws + 18874368);    // q[t][c], pre-scaled by 2^-3*log2e
  short* k_t  = (short*)(ws + 35651584);    // k[t][c]
  short* v_t  = (short*)(ws + 52428800);    // v in attn-tile cell layout
  short* a_bt = hid;
  float* qbp  = (float*)d_out;              // permuted bias scratch (d_out dead until gemmP)
  if (ws_size < 69206016) return;

  k_pre<<<4615, 256, 0, stream>>>(x, nw, nb, hid, qw, pw, qb, qwb, pwb, qbp);
  k_gemmQ<<<1536, 256, 0, stream>>>(qwb, hid, qbp, q_t, k_t, v_t);
  k_attn<<<1024, 256, 0, stream>>>(q_t, k_t, v_t, a_bt);
  k_gemmP<<<512, 256, 0, stream>>>(pwb, a_bt, pb, x, outp);
}